// Round 17
// baseline (183.615 us; speedup 1.0000x reference)
//
#include <hip/hip_runtime.h>
#include <cstddef>

#define N_TOK 4096
#define C_DIM 768
#define H_NUM 12
#define C3    2304
#define NSPLIT 2

typedef unsigned short u16;
using short8  = __attribute__((ext_vector_type(8))) short;
using floatx4 = __attribute__((ext_vector_type(4))) float;
using u16x4   = __attribute__((ext_vector_type(4))) u16;
using uint4v  = __attribute__((ext_vector_type(4))) unsigned;

#define K2SCALE 0.18033688011112043f  // (1/8) * log2(e), folded into Q at QKV epilogue

__device__ __forceinline__ u16 f2bf(float f) {
  union { float f; unsigned u; } v; v.f = f;
  unsigned r = v.u + 0x7FFFu + ((v.u >> 16) & 1u);
  return (u16)(r >> 16);
}

// truncate-pack two f32 -> two bf16 in one u32 (1 v_perm; bias cancels: l uses same P~)
__device__ __forceinline__ unsigned permpack(float a, float b) {
  union { float f; unsigned u; } x, y; x.f = a; y.f = b;
  return __builtin_amdgcn_perm(y.u, x.u, 0x07060302u);
}

// bare v_exp_f32 (libcall exp2f adds denormal-guard VALU; our inputs are range-safe)
__device__ __forceinline__ float aexp2(float x) {
  float r;
  asm("v_exp_f32 %0, %1" : "=v"(r) : "v"(x));
  return r;
}

__device__ __forceinline__ float arcp(float x) {
  float r;
  asm("v_rcp_f32 %0, %1" : "=v"(r) : "v"(x));
  return r;
}

// gfx950 register-pair <-> lane-bit exchanges.
__device__ __forceinline__ void pl_swap32(unsigned &a, unsigned &b) {
#if __has_builtin(__builtin_amdgcn_permlane32_swap)
  auto r = __builtin_amdgcn_permlane32_swap(a, b, false, false);
  a = r[0]; b = r[1];
#else
  asm("v_permlane32_swap_b32 %0, %1" : "+v"(a), "+v"(b));
#endif
}
__device__ __forceinline__ void pl_swap16(unsigned &a, unsigned &b) {
#if __has_builtin(__builtin_amdgcn_permlane16_swap)
  auto r = __builtin_amdgcn_permlane16_swap(a, b, false, false);
  a = r[0]; b = r[1];
#else
  asm("v_permlane16_swap_b32 %0, %1" : "+v"(a), "+v"(b));
#endif
}

// async global->LDS, 16B per lane. LDS dest must be wave-uniform base + lane*16.
__device__ __forceinline__ void gload_lds16(const void* g, void* l) {
  __builtin_amdgcn_global_load_lds(
      (const __attribute__((address_space(1))) unsigned int*)g,
      (__attribute__((address_space(3))) unsigned int*)l, 16, 0, 0);
}

// ---------- fused preprocessing: x f32->bf16 + weight transposes ----------
__global__ void k_pre(const float* __restrict__ x, u16* __restrict__ xb,
                      const float* __restrict__ wq, u16* __restrict__ wqT,
                      const float* __restrict__ wp, u16* __restrict__ wpT) {
  __shared__ float tile[32][33];
  const int b = blockIdx.x;
  if (b < 3072) {
    int i = b * 256 + threadIdx.x;
    float4 f = ((const float4*)x)[i];
    u16x4 o;
    o[0] = f2bf(f.x); o[1] = f2bf(f.y); o[2] = f2bf(f.z); o[3] = f2bf(f.w);
    ((u16x4*)xb)[i] = o;
    return;
  }
  const float* in; u16* out; int Cc, bx, by;
  if (b < 4800) { int t = b - 3072; in = wq; out = wqT; Cc = 2304; bx = t % 72; by = t / 72; }
  else          { int t = b - 4800; in = wp; out = wpT; Cc = 768;  bx = t % 24; by = t / 24; }
  const int R = 768;
  const int tx = threadIdx.x & 31;
  const int ty = threadIdx.x >> 5;
  const int c0 = bx * 32, r0 = by * 32;
#pragma unroll
  for (int i = 0; i < 32; i += 8)
    tile[ty + i][tx] = in[(size_t)(r0 + ty + i) * Cc + c0 + tx];
  __syncthreads();
#pragma unroll
  for (int i = 0; i < 32; i += 8)
    out[(size_t)(c0 + ty + i) * R + r0 + tx] = f2bf(tile[tx][ty + i]);
}

// ---------------- GEMM0: qkv = xb * wqkvT^T + bias (128x128 tile, BK=32) ----------------
// R16: vT epilogue de-scattered — per-wave 64x64 LDS transpose tile (aliases the
// As/Bs space, safe after the K-loop's final barrier; wave-private -> no extra
// __syncthreads). XOR chunk swizzle (c ^= hdl&15) keeps both LDS phases <=2-way
// (free, m136). Global vT stores become 4x128B segments/instruction instead of a
// 64-lane 8B scatter. Math bit-identical (same f2bf(acc+bc) to same bytes).
// bm = blockIdx.x (32 % 8 == 0) -> XCD row-banding (R13, T1).
__global__ __launch_bounds__(256)
void k_gemm_qkv(const u16* __restrict__ A, const u16* __restrict__ B,
                const float* __restrict__ bias, u16* __restrict__ qkv,
                u16* __restrict__ vT) {
  __shared__ u16 sm[16384];           // As = sm[0:8192), Bs = sm[8192:16384)
  const int K = C_DIM;
  const int tid  = threadIdx.x;
  const int wave = tid >> 6, lane = tid & 63, quad = lane >> 4, l16 = lane & 15;
  const int wrow = wave >> 1, wcol = wave & 1;
  const int bm = blockIdx.x, bn = blockIdx.y;   // bm fastest -> XCD row-banding
  const int r3 = l16 & 3;

  floatx4 acc[4][4];
#pragma unroll
  for (int i = 0; i < 4; ++i)
#pragma unroll
    for (int j = 0; j < 4; ++j)
#pragma unroll
      for (int r = 0; r < 4; ++r) acc[i][j][r] = 0.f;

  const int ar = tid >> 2;
  const int ac = ((tid & 3) ^ (ar & 3)) * 8;
  const u16* gA = A + (size_t)(bm * 128 + ar) * K + ac;
  const u16* gB = B + (size_t)(bn * 128 + ar) * K + ac;

  auto stage = [&](int b, int k0) {
    gload_lds16(gA + k0,                  &sm[b * 4096 + tid * 8]);
    gload_lds16(gA + k0 + (size_t)64 * K, &sm[b * 4096 + tid * 8 + 2048]);
    gload_lds16(gB + k0,                  &sm[8192 + b * 4096 + tid * 8]);
    gload_lds16(gB + k0 + (size_t)64 * K, &sm[8192 + b * 4096 + tid * 8 + 2048]);
  };

  stage(0, 0);
  __syncthreads();
  int buf = 0;
  for (int k0 = 0; k0 < K; k0 += 32) {
    if (k0 + 32 < K) stage(buf ^ 1, k0 + 32);
    short8 af[4], bf[4];
#pragma unroll
    for (int t = 0; t < 4; ++t) {
      af[t] = *(const short8*)&sm[buf * 4096 + (wrow * 64 + t * 16 + l16) * 32 + ((quad ^ r3) * 8)];
      bf[t] = *(const short8*)&sm[8192 + buf * 4096 + (wcol * 64 + t * 16 + l16) * 32 + ((quad ^ r3) * 8)];
    }
#pragma unroll
    for (int tm = 0; tm < 4; ++tm)
#pragma unroll
      for (int tn = 0; tn < 4; ++tn)
        acc[tm][tn] = __builtin_amdgcn_mfma_f32_16x16x32_bf16(af[tm], bf[tn], acc[tm][tn], 0, 0, 0);
    __syncthreads();
    buf ^= 1;
  }

  if (bn < 12) {
    // q,k path: row-major qkv, unchanged
    const float qs = (bn < 6) ? K2SCALE : 1.0f;
#pragma unroll
    for (int tn = 0; tn < 4; ++tn) {
      const int col = bn * 128 + wcol * 64 + tn * 16 + l16;
      const float bc = bias[col];
#pragma unroll
      for (int tm = 0; tm < 4; ++tm) {
        const int rowb = bm * 128 + wrow * 64 + tm * 16 + quad * 4;
#pragma unroll
        for (int r = 0; r < 4; ++r)
          qkv[(size_t)(rowb + r) * C3 + col] = f2bf((acc[tm][tn][r] + bc) * qs);
      }
    }
  } else {
    // v path: transpose through per-wave 64x64 LDS tile, then coalesced vT stores.
    // All waves passed the loop's final barrier -> LDS reuse is safe; region is
    // wave-private (sm + wave*4096) -> no inter-wave sync needed.
    u16* wv = &sm[wave * 4096];
    const int bn12 = bn - 12;
#pragma unroll
    for (int tn = 0; tn < 4; ++tn) {
      const int col = bn * 128 + wcol * 64 + tn * 16 + l16;
      const float bc = bias[col];
      const int hdl = tn * 16 + l16;            // local hd row 0..63
#pragma unroll
      for (int tm = 0; tm < 4; ++tm) {
        u16x4 pk;
#pragma unroll
        for (int r = 0; r < 4; ++r) pk[r] = f2bf(acc[tm][tn][r] + bc);
        const int c = tm * 4 + quad;            // 8B chunk index 0..15
        *(u16x4*)&wv[hdl * 64 + ((c ^ (hdl & 15)) * 4)] = pk;
      }
    }
    asm volatile("s_waitcnt lgkmcnt(0)" ::: "memory");
#pragma unroll
    for (int i = 0; i < 16; ++i) {
      const int hdl = i * 4 + quad;             // row 0..63
      u16x4 v = *(u16x4*)&wv[hdl * 64 + ((l16 ^ (hdl & 15)) * 4)];
      *(u16x4*)&vT[(size_t)(bn12 * 128 + wcol * 64 + hdl) * N_TOK
                   + bm * 128 + wrow * 64 + l16 * 4] = v;
    }
  }
}

// ---------------- flash attention v12 (R13 best-known, FROZEN) ----------------
// grid (24, 32): x = h*2+split, y = qt. 24 % 8 == 0 -> KV-stream sharers on one XCD
// (R8, FETCH 55->18.5->12.3 MB verified). 768 blocks = 3 blk/CU, all co-resident.
// NSPLIT=2, per-split buffers, plain coalesced stores (no atomics, no zero pass).
// Fixed-max softmax; P in registers (permlane quad-transpose); l via all-ones MFMA.
__global__ __launch_bounds__(256, 3)
void k_flash(const u16* __restrict__ qkv, const u16* __restrict__ vT,
             float* __restrict__ Opart, float* __restrict__ lpart) {
  __shared__ u16 Ks[2][64 * 64];
  __shared__ u16 Vs[2][64 * 64];   // Vs[d][m]
  const int tid  = threadIdx.x;
  const int wave = tid >> 6, lane = tid & 63, quad = lane >> 4, l16 = lane & 15;
  const int h = blockIdx.x >> 1, split = blockIdx.x & 1, qt = blockIdx.y;
  const int lr = tid >> 3;                     // 0..31 (32 rows per DMA pass)
  const int lc = ((tid & 7) ^ (lr & 7)) * 8;   // swizzled source chunk
  const int r7 = l16 & 7;
  const int kb = split * 2048;

  // Q fragments (B-operand) straight from global
  short8 bq[2][2];
#pragma unroll
  for (int qs = 0; qs < 2; ++qs)
#pragma unroll
    for (int ks = 0; ks < 2; ++ks)
      bq[qs][ks] = *(const short8*)&qkv[(size_t)(qt * 128 + wave * 32 + qs * 16 + l16) * C3
                                        + h * 64 + ks * 32 + quad * 8];

  const u16* gk = qkv + (size_t)lr * C3 + C_DIM + h * 64 + lc;
  const u16* gv = vT + (size_t)(h * 64 + lr) * N_TOK + lc;

  auto stage = [&](int b, int m0) {
#pragma unroll
    for (int p = 0; p < 2; ++p) {
      gload_lds16(gk + (size_t)(m0 + p * 32) * C3,    &Ks[b][p * 2048 + tid * 8]);
      gload_lds16(gv + (size_t)(p * 32) * N_TOK + m0, &Vs[b][p * 2048 + tid * 8]);
    }
  };

  floatx4 o0[4], o1[4], l0, l1, zv;
#pragma unroll
  for (int r = 0; r < 4; ++r) { zv[r] = 0.f; l0[r] = 0.f; l1[r] = 0.f; }
#pragma unroll
  for (int d = 0; d < 4; ++d)
#pragma unroll
    for (int r = 0; r < 4; ++r) { o0[d][r] = 0.f; o1[d][r] = 0.f; }

  short8 ones;
#pragma unroll
  for (int i = 0; i < 8; ++i) ones[i] = (short)0x3F80;  // bf16 1.0

  auto compute = [&](int b) __attribute__((always_inline)) {
    const u16* kbp = &Ks[b][0];
    const u16* vb  = &Vs[b][0];
    floatx4 s0[4], s1[4];
    __builtin_amdgcn_s_setprio(1);
#pragma unroll
    for (int tn = 0; tn < 4; ++tn) {
      short8 ak = *(const short8*)&kbp[(tn * 16 + l16) * 64 + (quad ^ r7) * 8];
      s0[tn] = __builtin_amdgcn_mfma_f32_16x16x32_bf16(ak, bq[0][0], zv, 0, 0, 0);
      s1[tn] = __builtin_amdgcn_mfma_f32_16x16x32_bf16(ak, bq[1][0], zv, 0, 0, 0);
    }
#pragma unroll
    for (int tn = 0; tn < 4; ++tn) {
      short8 ak = *(const short8*)&kbp[(tn * 16 + l16) * 64 + ((quad + 4) ^ r7) * 8];
      s0[tn] = __builtin_amdgcn_mfma_f32_16x16x32_bf16(ak, bq[0][1], s0[tn], 0, 0, 0);
      s1[tn] = __builtin_amdgcn_mfma_f32_16x16x32_bf16(ak, bq[1][1], s1[tn], 0, 0, 0);
    }
    __builtin_amdgcn_s_setprio(0);

    // softmax + pack: pk[tn][w] holds bf16 P for k = 16tn + 4quad + 2w,+1 at q=l16
    unsigned pk0[4][2], pk1[4][2];
#pragma unroll
    for (int tn = 0; tn < 4; ++tn) {
      pk0[tn][0] = permpack(aexp2(s0[tn][0]), aexp2(s0[tn][1]));
      pk0[tn][1] = permpack(aexp2(s0[tn][2]), aexp2(s0[tn][3]));
      pk1[tn][0] = permpack(aexp2(s1[tn][0]), aexp2(s1[tn][1]));
      pk1[tn][1] = permpack(aexp2(s1[tn][2]), aexp2(s1[tn][3]));
    }
    // in-register quad-transpose: 2 swaps per (t1,w) pair, both q-strips
#pragma unroll
    for (int t1 = 0; t1 < 2; ++t1)
#pragma unroll
      for (int w = 0; w < 2; ++w) {
        pl_swap32(pk0[2 * t1][w], pk0[2 * t1 + 1][w]);
        pl_swap16(pk0[2 * t1][w], pk0[2 * t1 + 1][w]);
        pl_swap32(pk1[2 * t1][w], pk1[2 * t1 + 1][w]);
        pl_swap16(pk1[2 * t1][w], pk1[2 * t1 + 1][w]);
      }

#pragma unroll
    for (int ks = 0; ks < 2; ++ks) {
      uint4v t0v, t1v;
      t0v[0] = pk0[2 * ks][0]; t0v[1] = pk0[2 * ks][1];
      t0v[2] = pk0[2 * ks + 1][0]; t0v[3] = pk0[2 * ks + 1][1];
      t1v[0] = pk1[2 * ks][0]; t1v[1] = pk1[2 * ks][1];
      t1v[2] = pk1[2 * ks + 1][0]; t1v[3] = pk1[2 * ks + 1][1];
      const short8 ap0 = __builtin_bit_cast(short8, t0v);
      const short8 ap1 = __builtin_bit_cast(short8, t1v);
      __builtin_amdgcn_s_setprio(1);
#pragma unroll
      for (int dt = 0; dt < 4; ++dt) {
        short8 bv = *(const short8*)&vb[(dt * 16 + l16) * 64 + ((quad + 4 * ks) ^ r7) * 8];
        o0[dt] = __builtin_amdgcn_mfma_f32_16x16x32_bf16(ap0, bv, o0[dt], 0, 0, 0);
        o1[dt] = __builtin_amdgcn_mfma_f32_16x16x32_bf16(ap1, bv, o1[dt], 0, 0, 0);
      }
      l0 = __builtin_amdgcn_mfma_f32_16x16x32_bf16(ap0, ones, l0, 0, 0, 0);
      l1 = __builtin_amdgcn_mfma_f32_16x16x32_bf16(ap1, ones, l1, 0, 0, 0);
      __builtin_amdgcn_s_setprio(0);
    }
  };

  stage(0, kb);
  __syncthreads();
  int m0 = kb + 64;
  for (int it2 = 0; it2 < 15; ++it2) {
    stage(1, m0); m0 += 64;
    compute(0);
    __syncthreads();
    stage(0, m0); m0 += 64;
    compute(1);
    __syncthreads();
  }
  stage(1, m0);
  compute(0);
  __syncthreads();
  compute(1);

  // plain coalesced stores into this split's private buffer (no atomics)
  const int rowg = qt * 128 + wave * 32 + quad * 4;   // + qs*16 + r
  float* Ob = Opart + (size_t)(split * H_NUM + h) * N_TOK * 64;
  float* lb = lpart + (size_t)(split * H_NUM + h) * N_TOK;
#pragma unroll
  for (int r = 0; r < 4; ++r) {
#pragma unroll
    for (int dt = 0; dt < 4; ++dt) {
      const int col = dt * 16 + l16;
      Ob[(size_t)(rowg + r) * 64 + col]      = o0[dt][r];
      Ob[(size_t)(rowg + 16 + r) * 64 + col] = o1[dt][r];
    }
    if (l16 == 0) {
      lb[rowg + r]      = l0[r];
      lb[rowg + 16 + r] = l1[r];
    }
  }
}

// ---------------- GEMM1 fused with combine: out = (sum_s O_s / sum_s l_s) * wprojT^T + bias ----------------
// 64x128 tile (R13 best-known); bm = blockIdx.x (64 % 8 == 0) -> XCD row-banding.
// stageA sums the two split partials, normalizes by arcp(l0+l1), f2bf, ds_write.
__global__ __launch_bounds__(256)
void k_gemm_proj(const float* __restrict__ Op, const float* __restrict__ lp,
                 const u16* __restrict__ B, const float* __restrict__ bias,
                 float* __restrict__ out) {
  __shared__ u16 As[2][64 * 32];
  __shared__ u16 Bs[2][128 * 32];
  const int K = C_DIM;
  const size_t OSTRIDE = (size_t)H_NUM * N_TOK * 64;
  const size_t LSTRIDE = (size_t)H_NUM * N_TOK;
  const int tid  = threadIdx.x;
  const int wave = tid >> 6, lane = tid & 63, quad = lane >> 4, l16 = lane & 15;
  const int wrow = wave >> 1, wcol = wave & 1;   // 2x2 waves over 64x128
  const int bm = blockIdx.x, bn = blockIdx.y;    // bm fastest -> XCD row-banding
  const int r3 = l16 & 3;

  floatx4 acc[2][4];
#pragma unroll
  for (int i = 0; i < 2; ++i)
#pragma unroll
    for (int j = 0; j < 4; ++j)
#pragma unroll
      for (int r = 0; r < 4; ++r) acc[i][j][r] = 0.f;

  const int ar = tid >> 2;                      // 0..63: row within A tile
  const int ac = ((tid & 3) ^ (ar & 3)) * 8;    // swizzled 8-col chunk
  const int qrow = bm * 64 + ar;
  const u16* gB = B + (size_t)(bn * 128 + ar) * K + ac;

  auto stageA = [&](int b, int k0) {
    const int hh = k0 >> 6;
    const size_t rowi = (size_t)hh * N_TOK + qrow;
    const float rl = arcp(lp[rowi] + lp[rowi + LSTRIDE]);
    const float* s0 = &Op[rowi * 64 + (k0 & 32) + ac];
    const float* s1 = s0 + OSTRIDE;
    float4 a0 = *(const float4*)s0;
    float4 a1 = *(const float4*)(s0 + 4);
    float4 b0 = *(const float4*)s1;
    float4 b1 = *(const float4*)(s1 + 4);
    u16x4 p0, p1;
    p0[0] = f2bf((a0.x + b0.x) * rl); p0[1] = f2bf((a0.y + b0.y) * rl);
    p0[2] = f2bf((a0.z + b0.z) * rl); p0[3] = f2bf((a0.w + b0.w) * rl);
    p1[0] = f2bf((a1.x + b1.x) * rl); p1[1] = f2bf((a1.y + b1.y) * rl);
    p1[2] = f2bf((a1.z + b1.z) * rl); p1[3] = f2bf((a1.w + b1.w) * rl);
    *(u16x4*)&As[b][tid * 8]     = p0;
    *(u16x4*)&As[b][tid * 8 + 4] = p1;
  };
  auto stageB = [&](int b, int k0) {
    gload_lds16(gB + k0,                  &Bs[b][tid * 8]);
    gload_lds16(gB + k0 + (size_t)64 * K, &Bs[b][tid * 8 + 2048]);
  };

  stageB(0, 0);
  stageA(0, 0);
  __syncthreads();
  int buf = 0;
  for (int k0 = 0; k0 < K; k0 += 32) {
    if (k0 + 32 < K) { stageB(buf ^ 1, k0 + 32); stageA(buf ^ 1, k0 + 32); }
    short8 af[2], bf[4];
#pragma unroll
    for (int t = 0; t < 2; ++t)
      af[t] = *(const short8*)&As[buf][(wrow * 32 + t * 16 + l16) * 32 + ((quad ^ r3) * 8)];
#pragma unroll
    for (int t = 0; t < 4; ++t)
      bf[t] = *(const short8*)&Bs[buf][(wcol * 64 + t * 16 + l16) * 32 + ((quad ^ r3) * 8)];
#pragma unroll
    for (int tm = 0; tm < 2; ++tm)
#pragma unroll
      for (int tn = 0; tn < 4; ++tn)
        acc[tm][tn] = __builtin_amdgcn_mfma_f32_16x16x32_bf16(af[tm], bf[tn], acc[tm][tn], 0, 0, 0);
    __syncthreads();
    buf ^= 1;
  }

#pragma unroll
  for (int tn = 0; tn < 4; ++tn) {
    const int col = bn * 128 + wcol * 64 + tn * 16 + l16;
    const float bc = bias[col];
#pragma unroll
    for (int tm = 0; tm < 2; ++tm) {
      const int rowb = bm * 64 + wrow * 32 + tm * 16 + quad * 4;
#pragma unroll
      for (int r = 0; r < 4; ++r)
        out[(size_t)(rowb + r) * C_DIM + col] = acc[tm][tn][r] + bc;
    }
  }
}

extern "C" void kernel_launch(void* const* d_in, const int* in_sizes, int n_in,
                              void* d_out, int out_size, void* d_ws, size_t ws_size,
                              hipStream_t stream) {
  const float* x      = (const float*)d_in[0];
  const float* w_qkv  = (const float*)d_in[1];
  const float* b_qkv  = (const float*)d_in[2];
  const float* w_proj = (const float*)d_in[3];
  const float* b_proj = (const float*)d_in[4];
  float* out = (float*)d_out;

  u16* xb     = (u16*)d_ws;                          // [4096][768]
  u16* wqkvT  = xb     + (size_t)N_TOK * C_DIM;      // [2304][768]
  u16* wprojT = wqkvT  + (size_t)C3 * C_DIM;         // [768][768]
  u16* qkv    = wprojT + (size_t)C_DIM * C_DIM;      // [4096][2304] (q,k; q pre-scaled)
  u16* vT     = qkv    + (size_t)N_TOK * C3;         // [768][4096]
  float* Opart = (float*)(vT + (size_t)C_DIM * N_TOK); // [2][12][4096][64] fp32 (25.2 MB)
  float* lpart = Opart + (size_t)NSPLIT * H_NUM * N_TOK * 64; // [2][12][4096] fp32
  // total ws: 61.8 MB (< 68 MB known-good)

  k_pre<<<5376, 256, 0, stream>>>(x, xb, w_qkv, wqkvT, w_proj, wprojT);
  k_gemm_qkv<<<dim3(N_TOK / 128, C3 / 128), 256, 0, stream>>>(xb, wqkvT, b_qkv, qkv, vT);
  k_flash<<<dim3(H_NUM * NSPLIT, N_TOK / 128), 256, 0, stream>>>(qkv, vT, Opart, lpart);
  k_gemm_proj<<<dim3(N_TOK / 64, C_DIM / 128), 256, 0, stream>>>(Opart, lpart, wprojT, b_proj, out);
}

// Round 18
// 179.049 us; speedup vs baseline: 1.0255x; 1.0255x over previous
//
#include <hip/hip_runtime.h>
#include <cstddef>

#define N_TOK 4096
#define C_DIM 768
#define H_NUM 12
#define C3    2304
#define NSPLIT 2

typedef unsigned short u16;
using short8  = __attribute__((ext_vector_type(8))) short;
using floatx4 = __attribute__((ext_vector_type(4))) float;
using u16x4   = __attribute__((ext_vector_type(4))) u16;
using uint4v  = __attribute__((ext_vector_type(4))) unsigned;

#define K2SCALE 0.18033688011112043f  // (1/8) * log2(e), folded into Q at QKV epilogue

__device__ __forceinline__ u16 f2bf(float f) {
  union { float f; unsigned u; } v; v.f = f;
  unsigned r = v.u + 0x7FFFu + ((v.u >> 16) & 1u);
  return (u16)(r >> 16);
}

// truncate-pack two f32 -> two bf16 in one u32 (1 v_perm; bias cancels: l uses same P~)
__device__ __forceinline__ unsigned permpack(float a, float b) {
  union { float f; unsigned u; } x, y; x.f = a; y.f = b;
  return __builtin_amdgcn_perm(y.u, x.u, 0x07060302u);
}

// bare v_exp_f32 (libcall exp2f adds denormal-guard VALU; our inputs are range-safe)
__device__ __forceinline__ float aexp2(float x) {
  float r;
  asm("v_exp_f32 %0, %1" : "=v"(r) : "v"(x));
  return r;
}

__device__ __forceinline__ float arcp(float x) {
  float r;
  asm("v_rcp_f32 %0, %1" : "=v"(r) : "v"(x));
  return r;
}

// gfx950 register-pair <-> lane-bit exchanges.
__device__ __forceinline__ void pl_swap32(unsigned &a, unsigned &b) {
#if __has_builtin(__builtin_amdgcn_permlane32_swap)
  auto r = __builtin_amdgcn_permlane32_swap(a, b, false, false);
  a = r[0]; b = r[1];
#else
  asm("v_permlane32_swap_b32 %0, %1" : "+v"(a), "+v"(b));
#endif
}
__device__ __forceinline__ void pl_swap16(unsigned &a, unsigned &b) {
#if __has_builtin(__builtin_amdgcn_permlane16_swap)
  auto r = __builtin_amdgcn_permlane16_swap(a, b, false, false);
  a = r[0]; b = r[1];
#else
  asm("v_permlane16_swap_b32 %0, %1" : "+v"(a), "+v"(b));
#endif
}

// async global->LDS, 16B per lane. LDS dest must be wave-uniform base + lane*16.
__device__ __forceinline__ void gload_lds16(const void* g, void* l) {
  __builtin_amdgcn_global_load_lds(
      (const __attribute__((address_space(1))) unsigned int*)g,
      (__attribute__((address_space(3))) unsigned int*)l, 16, 0, 0);
}

// ---------- fused preprocessing: x f32->bf16 + weight transposes ----------
// (Opart zeroing removed in R13: splits write disjoint buffers, no atomics)
__global__ void k_pre(const float* __restrict__ x, u16* __restrict__ xb,
                      const float* __restrict__ wq, u16* __restrict__ wqT,
                      const float* __restrict__ wp, u16* __restrict__ wpT) {
  __shared__ float tile[32][33];
  const int b = blockIdx.x;
  if (b < 3072) {
    int i = b * 256 + threadIdx.x;
    float4 f = ((const float4*)x)[i];
    u16x4 o;
    o[0] = f2bf(f.x); o[1] = f2bf(f.y); o[2] = f2bf(f.z); o[3] = f2bf(f.w);
    ((u16x4*)xb)[i] = o;
    return;
  }
  const float* in; u16* out; int Cc, bx, by;
  if (b < 4800) { int t = b - 3072; in = wq; out = wqT; Cc = 2304; bx = t % 72; by = t / 72; }
  else          { int t = b - 4800; in = wp; out = wpT; Cc = 768;  bx = t % 24; by = t / 24; }
  const int R = 768;
  const int tx = threadIdx.x & 31;
  const int ty = threadIdx.x >> 5;
  const int c0 = bx * 32, r0 = by * 32;
#pragma unroll
  for (int i = 0; i < 32; i += 8)
    tile[ty + i][tx] = in[(size_t)(r0 + ty + i) * Cc + c0 + tx];
  __syncthreads();
#pragma unroll
  for (int i = 0; i < 32; i += 8)
    out[(size_t)(c0 + ty + i) * R + r0 + tx] = f2bf(tile[tx][ty + i]);
}

// ---------------- GEMM0: qkv = xb * wqkvT^T + bias (128x128 tile, BK=32) ----------------
// R17 ERRATA: vT LDS-transpose epilogue regressed (+2.8 us) — L2 write-combining
// plus XCD row-banding already absorbed the 8B scatter; the extra LDS round-trip
// cost more than it saved. This is the R15-verified best config (180.8 us total).
// bm = blockIdx.x (32 % 8 == 0) -> XCD row-banding (R13, T1). Double-buffered
// prefetch K-loop (one barrier/iter).
__global__ __launch_bounds__(256)
void k_gemm_qkv(const u16* __restrict__ A, const u16* __restrict__ B,
                const float* __restrict__ bias, u16* __restrict__ qkv,
                u16* __restrict__ vT) {
  __shared__ u16 As[2][128 * 32];
  __shared__ u16 Bs[2][128 * 32];
  const int K = C_DIM;
  const int tid  = threadIdx.x;
  const int wave = tid >> 6, lane = tid & 63, quad = lane >> 4, l16 = lane & 15;
  const int wrow = wave >> 1, wcol = wave & 1;
  const int bm = blockIdx.x, bn = blockIdx.y;   // bm fastest -> XCD row-banding
  const int r3 = l16 & 3;

  floatx4 acc[4][4];
#pragma unroll
  for (int i = 0; i < 4; ++i)
#pragma unroll
    for (int j = 0; j < 4; ++j)
#pragma unroll
      for (int r = 0; r < 4; ++r) acc[i][j][r] = 0.f;

  const int ar = tid >> 2;
  const int ac = ((tid & 3) ^ (ar & 3)) * 8;
  const u16* gA = A + (size_t)(bm * 128 + ar) * K + ac;
  const u16* gB = B + (size_t)(bn * 128 + ar) * K + ac;

  auto stage = [&](int b, int k0) {
    gload_lds16(gA + k0,                  &As[b][tid * 8]);
    gload_lds16(gA + k0 + (size_t)64 * K, &As[b][tid * 8 + 2048]);
    gload_lds16(gB + k0,                  &Bs[b][tid * 8]);
    gload_lds16(gB + k0 + (size_t)64 * K, &Bs[b][tid * 8 + 2048]);
  };

  stage(0, 0);
  __syncthreads();
  int buf = 0;
  for (int k0 = 0; k0 < K; k0 += 32) {
    if (k0 + 32 < K) stage(buf ^ 1, k0 + 32);
    short8 af[4], bf[4];
#pragma unroll
    for (int t = 0; t < 4; ++t) {
      af[t] = *(const short8*)&As[buf][(wrow * 64 + t * 16 + l16) * 32 + ((quad ^ r3) * 8)];
      bf[t] = *(const short8*)&Bs[buf][(wcol * 64 + t * 16 + l16) * 32 + ((quad ^ r3) * 8)];
    }
#pragma unroll
    for (int tm = 0; tm < 4; ++tm)
#pragma unroll
      for (int tn = 0; tn < 4; ++tn)
        acc[tm][tn] = __builtin_amdgcn_mfma_f32_16x16x32_bf16(af[tm], bf[tn], acc[tm][tn], 0, 0, 0);
    __syncthreads();
    buf ^= 1;
  }

  const float qs = (bn < 6) ? K2SCALE : 1.0f;
#pragma unroll
  for (int tn = 0; tn < 4; ++tn) {
    const int col = bn * 128 + wcol * 64 + tn * 16 + l16;
    const float bc = bias[col];
    if (col < 1536) {
#pragma unroll
      for (int tm = 0; tm < 4; ++tm) {
        const int rowb = bm * 128 + wrow * 64 + tm * 16 + quad * 4;
#pragma unroll
        for (int r = 0; r < 4; ++r)
          qkv[(size_t)(rowb + r) * C3 + col] = f2bf((acc[tm][tn][r] + bc) * qs);
      }
    } else {
      const int hd_ = col - 1536;
#pragma unroll
      for (int tm = 0; tm < 4; ++tm) {
        const int rowb = bm * 128 + wrow * 64 + tm * 16 + quad * 4;
        u16x4 pk;
#pragma unroll
        for (int r = 0; r < 4; ++r) pk[r] = f2bf(acc[tm][tn][r] + bc);
        *(u16x4*)&vT[(size_t)hd_ * N_TOK + rowb] = pk;
      }
    }
  }
}

// ---------------- flash attention v12 (R13 best-known, FROZEN) ----------------
// grid (24, 32): x = h*2+split, y = qt. 24 % 8 == 0 -> KV-stream sharers on one XCD
// (R8, FETCH 55->18.5->12.3 MB verified). 768 blocks = 3 blk/CU, all co-resident.
// NSPLIT=2, per-split buffers, plain coalesced stores (no atomics, no zero pass).
// Fixed-max softmax; P in registers (permlane quad-transpose); l via all-ones MFMA.
__global__ __launch_bounds__(256, 3)
void k_flash(const u16* __restrict__ qkv, const u16* __restrict__ vT,
             float* __restrict__ Opart, float* __restrict__ lpart) {
  __shared__ u16 Ks[2][64 * 64];
  __shared__ u16 Vs[2][64 * 64];   // Vs[d][m]
  const int tid  = threadIdx.x;
  const int wave = tid >> 6, lane = tid & 63, quad = lane >> 4, l16 = lane & 15;
  const int h = blockIdx.x >> 1, split = blockIdx.x & 1, qt = blockIdx.y;
  const int lr = tid >> 3;                     // 0..31 (32 rows per DMA pass)
  const int lc = ((tid & 7) ^ (lr & 7)) * 8;   // swizzled source chunk
  const int r7 = l16 & 7;
  const int kb = split * 2048;

  // Q fragments (B-operand) straight from global
  short8 bq[2][2];
#pragma unroll
  for (int qs = 0; qs < 2; ++qs)
#pragma unroll
    for (int ks = 0; ks < 2; ++ks)
      bq[qs][ks] = *(const short8*)&qkv[(size_t)(qt * 128 + wave * 32 + qs * 16 + l16) * C3
                                        + h * 64 + ks * 32 + quad * 8];

  const u16* gk = qkv + (size_t)lr * C3 + C_DIM + h * 64 + lc;
  const u16* gv = vT + (size_t)(h * 64 + lr) * N_TOK + lc;

  auto stage = [&](int b, int m0) {
#pragma unroll
    for (int p = 0; p < 2; ++p) {
      gload_lds16(gk + (size_t)(m0 + p * 32) * C3,    &Ks[b][p * 2048 + tid * 8]);
      gload_lds16(gv + (size_t)(p * 32) * N_TOK + m0, &Vs[b][p * 2048 + tid * 8]);
    }
  };

  floatx4 o0[4], o1[4], l0, l1, zv;
#pragma unroll
  for (int r = 0; r < 4; ++r) { zv[r] = 0.f; l0[r] = 0.f; l1[r] = 0.f; }
#pragma unroll
  for (int d = 0; d < 4; ++d)
#pragma unroll
    for (int r = 0; r < 4; ++r) { o0[d][r] = 0.f; o1[d][r] = 0.f; }

  short8 ones;
#pragma unroll
  for (int i = 0; i < 8; ++i) ones[i] = (short)0x3F80;  // bf16 1.0

  auto compute = [&](int b) __attribute__((always_inline)) {
    const u16* kbp = &Ks[b][0];
    const u16* vb  = &Vs[b][0];
    floatx4 s0[4], s1[4];
    __builtin_amdgcn_s_setprio(1);
#pragma unroll
    for (int tn = 0; tn < 4; ++tn) {
      short8 ak = *(const short8*)&kbp[(tn * 16 + l16) * 64 + (quad ^ r7) * 8];
      s0[tn] = __builtin_amdgcn_mfma_f32_16x16x32_bf16(ak, bq[0][0], zv, 0, 0, 0);
      s1[tn] = __builtin_amdgcn_mfma_f32_16x16x32_bf16(ak, bq[1][0], zv, 0, 0, 0);
    }
#pragma unroll
    for (int tn = 0; tn < 4; ++tn) {
      short8 ak = *(const short8*)&kbp[(tn * 16 + l16) * 64 + ((quad + 4) ^ r7) * 8];
      s0[tn] = __builtin_amdgcn_mfma_f32_16x16x32_bf16(ak, bq[0][1], s0[tn], 0, 0, 0);
      s1[tn] = __builtin_amdgcn_mfma_f32_16x16x32_bf16(ak, bq[1][1], s1[tn], 0, 0, 0);
    }
    __builtin_amdgcn_s_setprio(0);

    // softmax + pack: pk[tn][w] holds bf16 P for k = 16tn + 4quad + 2w,+1 at q=l16
    unsigned pk0[4][2], pk1[4][2];
#pragma unroll
    for (int tn = 0; tn < 4; ++tn) {
      pk0[tn][0] = permpack(aexp2(s0[tn][0]), aexp2(s0[tn][1]));
      pk0[tn][1] = permpack(aexp2(s0[tn][2]), aexp2(s0[tn][3]));
      pk1[tn][0] = permpack(aexp2(s1[tn][0]), aexp2(s1[tn][1]));
      pk1[tn][1] = permpack(aexp2(s1[tn][2]), aexp2(s1[tn][3]));
    }
    // in-register quad-transpose: 2 swaps per (t1,w) pair, both q-strips
#pragma unroll
    for (int t1 = 0; t1 < 2; ++t1)
#pragma unroll
      for (int w = 0; w < 2; ++w) {
        pl_swap32(pk0[2 * t1][w], pk0[2 * t1 + 1][w]);
        pl_swap16(pk0[2 * t1][w], pk0[2 * t1 + 1][w]);
        pl_swap32(pk1[2 * t1][w], pk1[2 * t1 + 1][w]);
        pl_swap16(pk1[2 * t1][w], pk1[2 * t1 + 1][w]);
      }

#pragma unroll
    for (int ks = 0; ks < 2; ++ks) {
      uint4v t0v, t1v;
      t0v[0] = pk0[2 * ks][0]; t0v[1] = pk0[2 * ks][1];
      t0v[2] = pk0[2 * ks + 1][0]; t0v[3] = pk0[2 * ks + 1][1];
      t1v[0] = pk1[2 * ks][0]; t1v[1] = pk1[2 * ks][1];
      t1v[2] = pk1[2 * ks + 1][0]; t1v[3] = pk1[2 * ks + 1][1];
      const short8 ap0 = __builtin_bit_cast(short8, t0v);
      const short8 ap1 = __builtin_bit_cast(short8, t1v);
      __builtin_amdgcn_s_setprio(1);
#pragma unroll
      for (int dt = 0; dt < 4; ++dt) {
        short8 bv = *(const short8*)&vb[(dt * 16 + l16) * 64 + ((quad + 4 * ks) ^ r7) * 8];
        o0[dt] = __builtin_amdgcn_mfma_f32_16x16x32_bf16(ap0, bv, o0[dt], 0, 0, 0);
        o1[dt] = __builtin_amdgcn_mfma_f32_16x16x32_bf16(ap1, bv, o1[dt], 0, 0, 0);
      }
      l0 = __builtin_amdgcn_mfma_f32_16x16x32_bf16(ap0, ones, l0, 0, 0, 0);
      l1 = __builtin_amdgcn_mfma_f32_16x16x32_bf16(ap1, ones, l1, 0, 0, 0);
      __builtin_amdgcn_s_setprio(0);
    }
  };

  stage(0, kb);
  __syncthreads();
  int m0 = kb + 64;
  for (int it2 = 0; it2 < 15; ++it2) {
    stage(1, m0); m0 += 64;
    compute(0);
    __syncthreads();
    stage(0, m0); m0 += 64;
    compute(1);
    __syncthreads();
  }
  stage(1, m0);
  compute(0);
  __syncthreads();
  compute(1);

  // plain coalesced stores into this split's private buffer (no atomics)
  const int rowg = qt * 128 + wave * 32 + quad * 4;   // + qs*16 + r
  float* Ob = Opart + (size_t)(split * H_NUM + h) * N_TOK * 64;
  float* lb = lpart + (size_t)(split * H_NUM + h) * N_TOK;
#pragma unroll
  for (int r = 0; r < 4; ++r) {
#pragma unroll
    for (int dt = 0; dt < 4; ++dt) {
      const int col = dt * 16 + l16;
      Ob[(size_t)(rowg + r) * 64 + col]      = o0[dt][r];
      Ob[(size_t)(rowg + 16 + r) * 64 + col] = o1[dt][r];
    }
    if (l16 == 0) {
      lb[rowg + r]      = l0[r];
      lb[rowg + 16 + r] = l1[r];
    }
  }
}

// ---------------- GEMM1 fused with combine: out = (sum_s O_s / sum_s l_s) * wprojT^T + bias ----------------
// 64x128 tile (R13 best-known); bm = blockIdx.x (64 % 8 == 0) -> XCD row-banding.
// stageA sums the two split partials, normalizes by arcp(l0+l1), f2bf, ds_write
// to the standard LDS layout. dbuf hazard unchanged.
__global__ __launch_bounds__(256)
void k_gemm_proj(const float* __restrict__ Op, const float* __restrict__ lp,
                 const u16* __restrict__ B, const float* __restrict__ bias,
                 float* __restrict__ out) {
  __shared__ u16 As[2][64 * 32];
  __shared__ u16 Bs[2][128 * 32];
  const int K = C_DIM;
  const size_t OSTRIDE = (size_t)H_NUM * N_TOK * 64;
  const size_t LSTRIDE = (size_t)H_NUM * N_TOK;
  const int tid  = threadIdx.x;
  const int wave = tid >> 6, lane = tid & 63, quad = lane >> 4, l16 = lane & 15;
  const int wrow = wave >> 1, wcol = wave & 1;   // 2x2 waves over 64x128
  const int bm = blockIdx.x, bn = blockIdx.y;    // bm fastest -> XCD row-banding
  const int r3 = l16 & 3;

  floatx4 acc[2][4];
#pragma unroll
  for (int i = 0; i < 2; ++i)
#pragma unroll
    for (int j = 0; j < 4; ++j)
#pragma unroll
      for (int r = 0; r < 4; ++r) acc[i][j][r] = 0.f;

  const int ar = tid >> 2;                      // 0..63: row within A tile
  const int ac = ((tid & 3) ^ (ar & 3)) * 8;    // swizzled 8-col chunk
  const int qrow = bm * 64 + ar;
  const u16* gB = B + (size_t)(bn * 128 + ar) * K + ac;

  auto stageA = [&](int b, int k0) {
    const int hh = k0 >> 6;
    const size_t rowi = (size_t)hh * N_TOK + qrow;
    const float rl = arcp(lp[rowi] + lp[rowi + LSTRIDE]);
    const float* s0 = &Op[rowi * 64 + (k0 & 32) + ac];
    const float* s1 = s0 + OSTRIDE;
    float4 a0 = *(const float4*)s0;
    float4 a1 = *(const float4*)(s0 + 4);
    float4 b0 = *(const float4*)s1;
    float4 b1 = *(const float4*)(s1 + 4);
    u16x4 p0, p1;
    p0[0] = f2bf((a0.x + b0.x) * rl); p0[1] = f2bf((a0.y + b0.y) * rl);
    p0[2] = f2bf((a0.z + b0.z) * rl); p0[3] = f2bf((a0.w + b0.w) * rl);
    p1[0] = f2bf((a1.x + b1.x) * rl); p1[1] = f2bf((a1.y + b1.y) * rl);
    p1[2] = f2bf((a1.z + b1.z) * rl); p1[3] = f2bf((a1.w + b1.w) * rl);
    *(u16x4*)&As[b][tid * 8]     = p0;
    *(u16x4*)&As[b][tid * 8 + 4] = p1;
  };
  auto stageB = [&](int b, int k0) {
    gload_lds16(gB + k0,                  &Bs[b][tid * 8]);
    gload_lds16(gB + k0 + (size_t)64 * K, &Bs[b][tid * 8 + 2048]);
  };

  stageB(0, 0);
  stageA(0, 0);
  __syncthreads();
  int buf = 0;
  for (int k0 = 0; k0 < K; k0 += 32) {
    if (k0 + 32 < K) { stageB(buf ^ 1, k0 + 32); stageA(buf ^ 1, k0 + 32); }
    short8 af[2], bf[4];
#pragma unroll
    for (int t = 0; t < 2; ++t)
      af[t] = *(const short8*)&As[buf][(wrow * 32 + t * 16 + l16) * 32 + ((quad ^ r3) * 8)];
#pragma unroll
    for (int t = 0; t < 4; ++t)
      bf[t] = *(const short8*)&Bs[buf][(wcol * 64 + t * 16 + l16) * 32 + ((quad ^ r3) * 8)];
#pragma unroll
    for (int tm = 0; tm < 2; ++tm)
#pragma unroll
      for (int tn = 0; tn < 4; ++tn)
        acc[tm][tn] = __builtin_amdgcn_mfma_f32_16x16x32_bf16(af[tm], bf[tn], acc[tm][tn], 0, 0, 0);
    __syncthreads();
    buf ^= 1;
  }

#pragma unroll
  for (int tn = 0; tn < 4; ++tn) {
    const int col = bn * 128 + wcol * 64 + tn * 16 + l16;
    const float bc = bias[col];
#pragma unroll
    for (int tm = 0; tm < 2; ++tm) {
      const int rowb = bm * 64 + wrow * 32 + tm * 16 + quad * 4;
#pragma unroll
      for (int r = 0; r < 4; ++r)
        out[(size_t)(rowb + r) * C_DIM + col] = acc[tm][tn][r] + bc;
    }
  }
}

extern "C" void kernel_launch(void* const* d_in, const int* in_sizes, int n_in,
                              void* d_out, int out_size, void* d_ws, size_t ws_size,
                              hipStream_t stream) {
  const float* x      = (const float*)d_in[0];
  const float* w_qkv  = (const float*)d_in[1];
  const float* b_qkv  = (const float*)d_in[2];
  const float* w_proj = (const float*)d_in[3];
  const float* b_proj = (const float*)d_in[4];
  float* out = (float*)d_out;

  u16* xb     = (u16*)d_ws;                          // [4096][768]
  u16* wqkvT  = xb     + (size_t)N_TOK * C_DIM;      // [2304][768]
  u16* wprojT = wqkvT  + (size_t)C3 * C_DIM;         // [768][768]
  u16* qkv    = wprojT + (size_t)C_DIM * C_DIM;      // [4096][2304] (q,k; q pre-scaled)
  u16* vT     = qkv    + (size_t)N_TOK * C3;         // [768][4096]
  float* Opart = (float*)(vT + (size_t)C_DIM * N_TOK); // [2][12][4096][64] fp32 (25.2 MB)
  float* lpart = Opart + (size_t)NSPLIT * H_NUM * N_TOK * 64; // [2][12][4096] fp32
  // total ws: 61.8 MB (< 68 MB known-good)

  k_pre<<<5376, 256, 0, stream>>>(x, xb, w_qkv, wqkvT, w_proj, wprojT);
  k_gemm_qkv<<<dim3(N_TOK / 128, C3 / 128), 256, 0, stream>>>(xb, wqkvT, b_qkv, qkv, vT);
  k_flash<<<dim3(H_NUM * NSPLIT, N_TOK / 128), 256, 0, stream>>>(qkv, vT, Opart, lpart);
  k_gemm_proj<<<dim3(N_TOK / 64, C_DIM / 128), 256, 0, stream>>>(Opart, lpart, wprojT, b_proj, out);
}